// Round 1
// 419.024 us; speedup vs baseline: 1.0105x; 1.0105x over previous
//
#include <hip/hip_runtime.h>

#define D_FEAT 128
#define SUBS 8

typedef short bf16x8 __attribute__((ext_vector_type(8)));
typedef float f32x4 __attribute__((ext_vector_type(4)));

__device__ __forceinline__ unsigned short f2bf(float f) {
    unsigned u = __builtin_bit_cast(unsigned, f);
    u += 0x7FFF + ((u >> 16) & 1);   // round-to-nearest-even
    return (unsigned short)(u >> 16);
}

// ws int layout: [flag:64][scnt:8N (becomes cursor)][offsets:8N+1 pad][partials:4096][adj:E]
// then Wc[128*256] bf16, xb[N*64] uint (bf16x2)

// ---------------- K0: init ----------------
__global__ void init_kernel(int* __restrict__ scnt, long total, int* __restrict__ flag) {
    long gid = (long)blockIdx.x * blockDim.x + threadIdx.x;
    if (gid == 0) *flag = 1;
    if (gid < total) scnt[gid] = 0;
}

// ---------------- K1: detect int64 vs int32 edge_index ----------------
__global__ void detect_i64_kernel(const int* __restrict__ ei32, int* __restrict__ flag) {
    int t = threadIdx.x;
    int nonzero = 0;
    for (int i = t; i < 4096; i += 256) {
        if (ei32[2 * i + 1] != 0) nonzero = 1;
    }
    if (nonzero) atomicAnd(flag, 0);
}

__device__ __forceinline__ void decode_edge(const int* ei, int e, int E, int is64,
                                            int& src, int& dst) {
    if (is64) {
        src = ei[2 * e];
        dst = ei[2 * E + 2 * e];
    } else {
        src = ei[e];
        dst = ei[E + e];
    }
}

__device__ __forceinline__ int decode_dst(const int* ei, int e, int E, int is64) {
    return is64 ? ei[2 * E + 2 * e] : ei[E + e];
}

// ---------------- K2: x -> bf16 ----------------
__global__ void xb_kernel(const float4* __restrict__ x4, uint2* __restrict__ xb2,
                          long total4) {
    long gid = (long)blockIdx.x * blockDim.x + threadIdx.x;
    if (gid >= total4) return;
    float4 v = x4[gid];
    uint2 o;
    o.x = (unsigned)f2bf(v.x) | ((unsigned)f2bf(v.y) << 16);
    o.y = (unsigned)f2bf(v.z) | ((unsigned)f2bf(v.w) << 16);
    xb2[gid] = o;
}

// ---------------- K3: pack [Wl|Wr] -> Wc[n][k] bf16 ----------------
__global__ void wc_kernel(const float* __restrict__ Wl, const float* __restrict__ Wr,
                          unsigned short* __restrict__ Wc) {
    int n = blockIdx.x;
    int k = threadIdx.x;
    float w = (k < 128) ? Wl[n * 128 + k] : Wr[n * 128 + (k - 128)];
    Wc[n * 256 + k] = f2bf(w);
}

// ---------------- K4: degree count, XCD-sliced (s = blockIdx&7) ----------------
__global__ void count_kernel(const int* __restrict__ ei, int* __restrict__ scnt,
                             const int* __restrict__ flag, int E, int N) {
    int e = blockIdx.x * blockDim.x + threadIdx.x;
    if (e >= E) return;
    int is64 = *flag;
    int dst = decode_dst(ei, e, E, is64);
    int s = blockIdx.x & (SUBS - 1);
    atomicAdd(&scnt[(long)s * N + dst], 1);
}

// ---------------- K5a: block-local exclusive scan over 8N ----------------
__global__ __launch_bounds__(256) void scan1_kernel(const int* __restrict__ scnt,
                                                    int* __restrict__ offsets,
                                                    int* __restrict__ partials, long total) {
    __shared__ int s[256];
    int t = threadIdx.x;
    long gid = (long)blockIdx.x * 256 + t;
    int v = (gid < total) ? scnt[gid] : 0;
    s[t] = v;
    __syncthreads();
    for (int off = 1; off < 256; off <<= 1) {
        int add = (t >= off) ? s[t - off] : 0;
        __syncthreads();
        s[t] += add;
        __syncthreads();
    }
    if (gid < total) offsets[gid] = s[t] - v;
    if (t == 255) partials[blockIdx.x] = s[255];
}

// ---------------- K5b: serial-chunk scan of partials (1 block) ----------------
__global__ __launch_bounds__(256) void scan2_kernel(int* __restrict__ partials, int P,
                                                    int* __restrict__ offsets,
                                                    long total, int E) {
    __shared__ int s[256];
    int t = threadIdx.x;
    int run = 0;
    for (int base = 0; base < P; base += 256) {
        int v = (base + t < P) ? partials[base + t] : 0;
        s[t] = v;
        __syncthreads();
        for (int off = 1; off < 256; off <<= 1) {
            int add = (t >= off) ? s[t - off] : 0;
            __syncthreads();
            s[t] += add;
            __syncthreads();
        }
        if (base + t < P) partials[base + t] = s[t] - v + run;
        run += s[255];
        __syncthreads();
    }
    if (t == 0) offsets[total] = E;
}

// ---------------- K5c: finalize offsets, init cursor (reuses scnt) ----------------
__global__ void scan3_kernel(int* __restrict__ offsets, const int* __restrict__ partials,
                             int* __restrict__ cursor, long total) {
    long gid = (long)blockIdx.x * blockDim.x + threadIdx.x;
    if (gid >= total) return;
    int o = offsets[gid] + partials[blockIdx.x];
    offsets[gid] = o;
    cursor[gid] = o;
}

// ---------------- K6: fill adjacency, XCD-sliced ----------------
__global__ void fill_kernel(const int* __restrict__ ei, int* __restrict__ cursor,
                            int* __restrict__ adj, const int* __restrict__ flag,
                            int E, int N) {
    int e = blockIdx.x * blockDim.x + threadIdx.x;
    if (e >= E) return;
    int is64 = *flag;
    int src, dst;
    decode_edge(ei, e, E, is64, src, dst);
    int s = blockIdx.x & (SUBS - 1);
    int slot = atomicAdd(&cursor[(long)s * N + dst], 1);
    adj[slot] = src;
}

__device__ __forceinline__ void acc_row(float* acc, uint4 v) {
    acc[0] += __builtin_bit_cast(float, v.x << 16);
    acc[1] += __builtin_bit_cast(float, v.x & 0xFFFF0000u);
    acc[2] += __builtin_bit_cast(float, v.y << 16);
    acc[3] += __builtin_bit_cast(float, v.y & 0xFFFF0000u);
    acc[4] += __builtin_bit_cast(float, v.z << 16);
    acc[5] += __builtin_bit_cast(float, v.z & 0xFFFF0000u);
    acc[6] += __builtin_bit_cast(float, v.w << 16);
    acc[7] += __builtin_bit_cast(float, v.w & 0xFFFF0000u);
}

// ---------------- K7: fused gather + MFMA GEMM, 16 nodes per block ----------------
// Gather, per node (wave-collective, high MLP):
//   1. all 64 lanes fetch the 4 nodes' 16 segment offsets in ONE load
//   2. per 64-edge batch: lane i maps itself to edge i via uniform prefix over
//      the 8 segments, loads its adj entry (one load for <=64 edges)
//   3. quad-split row loads: quad q loads edge (bb+q+4j)'s row as dwordx4
//      (16B/lane x 16 lanes = 256B row) -> 4 independent rows in flight/iter,
//      16 edges per iteration. Quad partials combined via shfl_xor(16|32).
__global__ __launch_bounds__(256) void gg_kernel(
    const unsigned int* __restrict__ xb, const int* __restrict__ offsets,
    const int* __restrict__ adj, const unsigned short* __restrict__ Wc,
    const float* __restrict__ bl, float* __restrict__ out, int N) {
    __shared__ __align__(16) unsigned short A[16 * 264];

    const int t = threadIdx.x;
    const int wv = t >> 6;
    const int lane = t & 63;
    const int n0 = blockIdx.x * 16;
    const int fq = lane & 15;   // position within quad
    const int qd = lane >> 4;   // quad id

    // phase 1a: one wave-wide load covers segment offsets for all 4 of this
    // wave's nodes: lane = {q:2}{endbit:1}{slice:3}
    {
    }
    const int nq = n0 + wv * 4 + (lane >> 4);
    const int sliceA = lane & 7;
    const int ebit = (lane >> 3) & 1;
    const int opre = offsets[(long)sliceA * N + min(nq, N - 1) + ebit];

    // own rows for the 4 nodes (independent loads, issue up front)
    unsigned xv[4];
#pragma unroll
    for (int q = 0; q < 4; ++q) {
        int n = n0 + wv * 4 + q;
        xv[q] = (n < N) ? xb[(long)n * 64 + lane] : 0u;
    }

    // phase 1b: gather (wave w handles rows w*4..w*4+3); n<N is wave-uniform
    for (int q = 0; q < 4; ++q) {
        const int r = wv * 4 + q;
        const int n = n0 + r;
        float acc[8] = {0.f, 0.f, 0.f, 0.f, 0.f, 0.f, 0.f, 0.f};
        int deg = 0;
        if (n < N) {
            int st_s[8], len_s[8];
#pragma unroll
            for (int s = 0; s < 8; ++s) {
                int sts = __shfl(opre, q * 16 + s);
                int ens = __shfl(opre, q * 16 + 8 + s);
                st_s[s] = sts;
                len_s[s] = ens - sts;
                deg += len_s[s];
            }
            for (int base = 0; base < deg; base += 64) {
                int i = base + lane;
                int gidx = -1;
                int cum = 0;
#pragma unroll
                for (int s = 0; s < 8; ++s) {
                    if (i >= cum && i < cum + len_s[s]) gidx = st_s[s] + (i - cum);
                    cum += len_s[s];
                }
                int adjv = (gidx >= 0) ? adj[gidx] : 0;
                int cnt = min(64, deg - base);
                for (int bb = 0; bb < cnt; bb += 16) {
                    int e0 = bb + qd;
                    int e1 = e0 + 4;
                    int e2 = e0 + 8;
                    int e3 = e0 + 12;
                    int s0 = __shfl(adjv, e0);
                    int s1 = __shfl(adjv, e1);
                    int s2 = __shfl(adjv, e2);
                    int s3 = __shfl(adjv, e3);
                    const uint4 z = {0u, 0u, 0u, 0u};
                    uint4 v0 = (e0 < cnt) ? *(const uint4*)&xb[(long)s0 * 64 + fq * 4] : z;
                    uint4 v1 = (e1 < cnt) ? *(const uint4*)&xb[(long)s1 * 64 + fq * 4] : z;
                    uint4 v2 = (e2 < cnt) ? *(const uint4*)&xb[(long)s2 * 64 + fq * 4] : z;
                    uint4 v3 = (e3 < cnt) ? *(const uint4*)&xb[(long)s3 * 64 + fq * 4] : z;
                    acc_row(acc, v0);
                    acc_row(acc, v1);
                    acc_row(acc, v2);
                    acc_row(acc, v3);
                }
            }
        }
        // combine quad partials: feature fq*8+j lives in lanes fq, fq+16, fq+32, fq+48
#pragma unroll
        for (int j = 0; j < 8; ++j) {
            acc[j] += __shfl_xor(acc[j], 16);
            acc[j] += __shfl_xor(acc[j], 32);
        }
        float iv = 1.0f / (float)max(deg, 1);
        if (qd == 0) {
            uint4 o;
            o.x = (unsigned)f2bf(acc[0] * iv) | ((unsigned)f2bf(acc[1] * iv) << 16);
            o.y = (unsigned)f2bf(acc[2] * iv) | ((unsigned)f2bf(acc[3] * iv) << 16);
            o.z = (unsigned)f2bf(acc[4] * iv) | ((unsigned)f2bf(acc[5] * iv) << 16);
            o.w = (unsigned)f2bf(acc[6] * iv) | ((unsigned)f2bf(acc[7] * iv) << 16);
            *(uint4*)&A[r * 264 + fq * 8] = o;
        }
        *(unsigned*)&A[r * 264 + 128 + 2 * lane] = xv[q];
    }
    __syncthreads();

    // phase 2: MFMA — wave w computes cols [w*32, w*32+32)
    const int l15 = lane & 15;
    const int quad = lane >> 4;
    f32x4 acc[2];
    acc[0] = (f32x4){0.f, 0.f, 0.f, 0.f};
    acc[1] = (f32x4){0.f, 0.f, 0.f, 0.f};

#pragma unroll
    for (int kc = 0; kc < 8; ++kc) {
        const int k0 = kc * 32;
        bf16x8 af = *(const bf16x8*)&A[l15 * 264 + k0 + quad * 8];
#pragma unroll
        for (int nt = 0; nt < 2; ++nt) {
            int col = wv * 32 + nt * 16 + l15;
            bf16x8 bf = *(const bf16x8*)&Wc[col * 256 + k0 + quad * 8];
            acc[nt] = __builtin_amdgcn_mfma_f32_16x16x32_bf16(af, bf, acc[nt], 0, 0, 0);
        }
    }

    // epilogue: C/D layout col=lane&15, row=quad*4+reg
#pragma unroll
    for (int nt = 0; nt < 2; ++nt) {
        int col = wv * 32 + nt * 16 + l15;
        float bias = bl[col];
#pragma unroll
        for (int r = 0; r < 4; ++r) {
            int node = n0 + quad * 4 + r;
            if (node < N) out[(long)node * 128 + col] = acc[nt][r] + bias;
        }
    }
}

extern "C" void kernel_launch(void* const* d_in, const int* in_sizes, int n_in,
                              void* d_out, int out_size, void* d_ws, size_t ws_size,
                              hipStream_t stream) {
    const float* x = (const float*)d_in[0];
    const int* ei = (const int*)d_in[1];
    const float* Wl = (const float*)d_in[2];
    const float* bl = (const float*)d_in[3];
    const float* Wr = (const float*)d_in[4];
    float* out = (float*)d_out;

    const int N = in_sizes[0] / D_FEAT;  // 100000
    const int E = in_sizes[1] / 2;       // 1600000
    const long SUBN = (long)SUBS * N;    // 800000

    int* wsI = (int*)d_ws;
    int* flag = wsI;                       // 64
    int* scnt = flag + 64;                 // 8N (doubles as cursor)
    int* offsets = scnt + SUBN;            // 8N+1 (+pad to 64)
    int* partials = offsets + SUBN + 64;   // 4096
    int* adj = partials + 4096;            // E
    unsigned short* Wc = (unsigned short*)(adj + E);        // 64KB
    unsigned int* xb = (unsigned int*)(Wc + 128 * 256);     // N*64 uints

    const int P = (int)((SUBN + 255) / 256);  // 3125

    init_kernel<<<P, 256, 0, stream>>>(scnt, SUBN, flag);
    detect_i64_kernel<<<1, 256, 0, stream>>>(ei, flag);
    xb_kernel<<<(int)(((long)N * 32 + 255) / 256), 256, 0, stream>>>(
        (const float4*)x, (uint2*)xb, (long)N * 32);
    wc_kernel<<<128, 256, 0, stream>>>(Wl, Wr, Wc);
    count_kernel<<<(E + 255) / 256, 256, 0, stream>>>(ei, scnt, flag, E, N);
    scan1_kernel<<<P, 256, 0, stream>>>(scnt, offsets, partials, SUBN);
    scan2_kernel<<<1, 256, 0, stream>>>(partials, P, offsets, SUBN, E);
    scan3_kernel<<<P, 256, 0, stream>>>(offsets, partials, scnt, SUBN);
    fill_kernel<<<(E + 255) / 256, 256, 0, stream>>>(ei, scnt, adj, flag, E, N);
    gg_kernel<<<(N + 15) / 16, 256, 0, stream>>>(xb, offsets, adj, Wc, bl, out, N);
}

// Round 2
// 398.859 us; speedup vs baseline: 1.0616x; 1.0506x over previous
//
#include <hip/hip_runtime.h>

#define D_FEAT 128
#define CAP 32
#define SPILLCAP (1 << 18)

typedef short bf16x8 __attribute__((ext_vector_type(8)));
typedef float f32x4 __attribute__((ext_vector_type(4)));

__device__ __forceinline__ unsigned short f2bf(float f) {
    unsigned u = __builtin_bit_cast(unsigned, f);
    u += 0x7FFF + ((u >> 16) & 1);   // round-to-nearest-even
    return (unsigned short)(u >> 16);
}

// ws int layout: [flag:64][cursor:N][spillcnt:64][spill:2*SPILLCAP][adj:N*CAP]
// then Wc[128*256] bf16, xb[N*64] uint (bf16x2)

// ---------------- K0: init ----------------
__global__ void init_kernel(int* __restrict__ cursor, int N, int* __restrict__ flag,
                            int* __restrict__ spillcnt) {
    int gid = blockIdx.x * blockDim.x + threadIdx.x;
    if (gid == 0) {
        *flag = 1;
        *spillcnt = 0;
    }
    if (gid < N) cursor[gid] = 0;
}

// ---------------- K1: detect int64 vs int32 edge_index ----------------
__global__ void detect_i64_kernel(const int* __restrict__ ei32, int* __restrict__ flag) {
    int t = threadIdx.x;
    int nonzero = 0;
    for (int i = t; i < 4096; i += 256) {
        if (ei32[2 * i + 1] != 0) nonzero = 1;
    }
    if (nonzero) atomicAnd(flag, 0);
}

__device__ __forceinline__ void decode_edge(const int* ei, int e, int E, int is64,
                                            int& src, int& dst) {
    if (is64) {
        src = ei[2 * e];
        dst = ei[2 * E + 2 * e];
    } else {
        src = ei[e];
        dst = ei[E + e];
    }
}

// ---------------- K2: x -> bf16 ----------------
__global__ void xb_kernel(const float4* __restrict__ x4, uint2* __restrict__ xb2,
                          long total4) {
    long gid = (long)blockIdx.x * blockDim.x + threadIdx.x;
    if (gid >= total4) return;
    float4 v = x4[gid];
    uint2 o;
    o.x = (unsigned)f2bf(v.x) | ((unsigned)f2bf(v.y) << 16);
    o.y = (unsigned)f2bf(v.z) | ((unsigned)f2bf(v.w) << 16);
    xb2[gid] = o;
}

// ---------------- K3: pack [Wl|Wr] -> Wc[n][k] bf16 ----------------
__global__ void wc_kernel(const float* __restrict__ Wl, const float* __restrict__ Wr,
                          unsigned short* __restrict__ Wc) {
    int n = blockIdx.x;
    int k = threadIdx.x;
    float w = (k < 128) ? Wl[n * 128 + k] : Wr[n * 128 + (k - 128)];
    Wc[n * 256 + k] = f2bf(w);
}

// ---------------- K4: single-pass bucketed CSR fill ----------------
// slot = atomicAdd(cursor[dst]); first CAP edges land in the node's bucket,
// overflow goes to the spill list (fixed up exactly by spill_kernel).
__global__ void fill_kernel(const int* __restrict__ ei, int* __restrict__ cursor,
                            int* __restrict__ adj, int* __restrict__ spillcnt,
                            int* __restrict__ spill, const int* __restrict__ flag,
                            int E, int N) {
    int e = blockIdx.x * blockDim.x + threadIdx.x;
    if (e >= E) return;
    int is64 = *flag;
    int src, dst;
    decode_edge(ei, e, E, is64, src, dst);
    int slot = atomicAdd(&cursor[dst], 1);
    if (slot < CAP) {
        adj[(long)dst * CAP + slot] = src;
    } else {
        int sp = atomicAdd(spillcnt, 1);
        if (sp < SPILLCAP) {
            spill[2 * sp] = src;
            spill[2 * sp + 1] = dst;
        }
    }
}

__device__ __forceinline__ void acc_row(float* acc, uint4 v) {
    acc[0] += __builtin_bit_cast(float, v.x << 16);
    acc[1] += __builtin_bit_cast(float, v.x & 0xFFFF0000u);
    acc[2] += __builtin_bit_cast(float, v.y << 16);
    acc[3] += __builtin_bit_cast(float, v.y & 0xFFFF0000u);
    acc[4] += __builtin_bit_cast(float, v.z << 16);
    acc[5] += __builtin_bit_cast(float, v.z & 0xFFFF0000u);
    acc[6] += __builtin_bit_cast(float, v.w << 16);
    acc[7] += __builtin_bit_cast(float, v.w & 0xFFFF0000u);
}

// ---------------- K5: fused gather + MFMA GEMM, 16 nodes per block ----------------
// Per wave: 4 nodes. deg = cursor[n] (one load). Bucket is contiguous at
// adj[n*CAP], so edge i maps directly (no segment search). Quad-split row
// loads: quad q loads edge (bb+q+4j)'s row as dwordx4 (16B/lane x 16 lanes
// = 256B row) -> 4 independent rows in flight, 16 edges per iteration.
__global__ __launch_bounds__(256) void gg_kernel(
    const unsigned int* __restrict__ xb, const int* __restrict__ cursor,
    const int* __restrict__ adj, const unsigned short* __restrict__ Wc,
    const float* __restrict__ bl, float* __restrict__ out, int N) {
    __shared__ __align__(16) unsigned short A[16 * 264];

    const int t = threadIdx.x;
    const int wv = t >> 6;
    const int lane = t & 63;
    const int n0 = blockIdx.x * 16;
    const int fq = lane & 15;   // position within quad
    const int qd = lane >> 4;   // quad id

    // degrees for this wave's 4 nodes (lane q holds node q's degree)
    int degpre = 0;
    {
        int nn = n0 + wv * 4 + (lane & 3);
        if (nn < N) degpre = cursor[nn];
    }

    // own rows for the 4 nodes (independent loads, issue up front)
    unsigned xv[4];
#pragma unroll
    for (int q = 0; q < 4; ++q) {
        int n = n0 + wv * 4 + q;
        xv[q] = (n < N) ? xb[(long)n * 64 + lane] : 0u;
    }

    for (int q = 0; q < 4; ++q) {
        const int r = wv * 4 + q;
        const int n = n0 + r;
        float acc[8] = {0.f, 0.f, 0.f, 0.f, 0.f, 0.f, 0.f, 0.f};
        const int deg = __shfl(degpre, q);
        const int cnt = min(deg, CAP);
        if (n < N && cnt > 0) {
            int adjv = (lane < cnt) ? adj[(long)n * CAP + lane] : 0;
            for (int bb = 0; bb < cnt; bb += 16) {
                int e0 = bb + qd;
                int e1 = e0 + 4;
                int e2 = e0 + 8;
                int e3 = e0 + 12;
                int s0 = __shfl(adjv, e0);
                int s1 = __shfl(adjv, e1);
                int s2 = __shfl(adjv, e2);
                int s3 = __shfl(adjv, e3);
                const uint4 z = {0u, 0u, 0u, 0u};
                uint4 v0 = (e0 < cnt) ? *(const uint4*)&xb[(long)s0 * 64 + fq * 4] : z;
                uint4 v1 = (e1 < cnt) ? *(const uint4*)&xb[(long)s1 * 64 + fq * 4] : z;
                uint4 v2 = (e2 < cnt) ? *(const uint4*)&xb[(long)s2 * 64 + fq * 4] : z;
                uint4 v3 = (e3 < cnt) ? *(const uint4*)&xb[(long)s3 * 64 + fq * 4] : z;
                acc_row(acc, v0);
                acc_row(acc, v1);
                acc_row(acc, v2);
                acc_row(acc, v3);
            }
        }
        // combine quad partials: feature fq*8+j lives in lanes fq, fq+16, fq+32, fq+48
#pragma unroll
        for (int j = 0; j < 8; ++j) {
            acc[j] += __shfl_xor(acc[j], 16);
            acc[j] += __shfl_xor(acc[j], 32);
        }
        float iv = 1.0f / (float)max(deg, 1);
        if (qd == 0) {
            uint4 o;
            o.x = (unsigned)f2bf(acc[0] * iv) | ((unsigned)f2bf(acc[1] * iv) << 16);
            o.y = (unsigned)f2bf(acc[2] * iv) | ((unsigned)f2bf(acc[3] * iv) << 16);
            o.z = (unsigned)f2bf(acc[4] * iv) | ((unsigned)f2bf(acc[5] * iv) << 16);
            o.w = (unsigned)f2bf(acc[6] * iv) | ((unsigned)f2bf(acc[7] * iv) << 16);
            *(uint4*)&A[r * 264 + fq * 8] = o;
        }
        *(unsigned*)&A[r * 264 + 128 + 2 * lane] = xv[q];
    }
    __syncthreads();

    // phase 2: MFMA — wave w computes cols [w*32, w*32+32)
    const int l15 = lane & 15;
    const int quad = lane >> 4;
    f32x4 acc[2];
    acc[0] = (f32x4){0.f, 0.f, 0.f, 0.f};
    acc[1] = (f32x4){0.f, 0.f, 0.f, 0.f};

#pragma unroll
    for (int kc = 0; kc < 8; ++kc) {
        const int k0 = kc * 32;
        bf16x8 af = *(const bf16x8*)&A[l15 * 264 + k0 + quad * 8];
#pragma unroll
        for (int nt = 0; nt < 2; ++nt) {
            int col = wv * 32 + nt * 16 + l15;
            bf16x8 bf = *(const bf16x8*)&Wc[col * 256 + k0 + quad * 8];
            acc[nt] = __builtin_amdgcn_mfma_f32_16x16x32_bf16(af, bf, acc[nt], 0, 0, 0);
        }
    }

    // epilogue: C/D layout col=lane&15, row=quad*4+reg
#pragma unroll
    for (int nt = 0; nt < 2; ++nt) {
        int col = wv * 32 + nt * 16 + l15;
        float bias = bl[col];
#pragma unroll
        for (int r = 0; r < 4; ++r) {
            int node = n0 + quad * 4 + r;
            if (node < N) out[(long)node * 128 + col] = acc[nt][r] + bias;
        }
    }
}

// ---------------- K6: exact spill fixup (normally 0 iterations) ----------------
// For each spilled edge: out[dst][c] += (Wl[c] . x[src]) / deg[dst], in f32.
__global__ __launch_bounds__(256) void spill_kernel(
    const float* __restrict__ x, const float* __restrict__ Wl,
    const int* __restrict__ cursor, const int* __restrict__ spillcnt,
    const int* __restrict__ spill, float* __restrict__ out) {
    const int wv = threadIdx.x >> 6;
    const int lane = threadIdx.x & 63;
    const int sc = min(*spillcnt, SPILLCAP);
    for (int i = blockIdx.x * 4 + wv; i < sc; i += gridDim.x * 4) {
        int src = spill[2 * i];
        int dst = spill[2 * i + 1];
        float inv = 1.0f / (float)max(cursor[dst], 1);
#pragma unroll
        for (int cc = 0; cc < 2; ++cc) {
            int c = lane + cc * 64;
            float s = 0.0f;
            for (int k = 0; k < 128; k += 4) {
                float4 w4 = *(const float4*)&Wl[c * 128 + k];
                float4 x4 = *(const float4*)&x[(long)src * 128 + k];
                s += w4.x * x4.x + w4.y * x4.y + w4.z * x4.z + w4.w * x4.w;
            }
            atomicAdd(&out[(long)dst * 128 + c], s * inv);
        }
    }
}

extern "C" void kernel_launch(void* const* d_in, const int* in_sizes, int n_in,
                              void* d_out, int out_size, void* d_ws, size_t ws_size,
                              hipStream_t stream) {
    const float* x = (const float*)d_in[0];
    const int* ei = (const int*)d_in[1];
    const float* Wl = (const float*)d_in[2];
    const float* bl = (const float*)d_in[3];
    const float* Wr = (const float*)d_in[4];
    float* out = (float*)d_out;

    const int N = in_sizes[0] / D_FEAT;  // 100000
    const int E = in_sizes[1] / 2;       // 1600000

    int* wsI = (int*)d_ws;
    int* flag = wsI;                         // 64
    int* cursor = flag + 64;                 // N (degree after fill)
    int* spillcnt = cursor + N;              // 64
    int* spill = spillcnt + 64;              // 2*SPILLCAP
    int* adj = spill + 2 * SPILLCAP;         // N*CAP
    unsigned short* Wc = (unsigned short*)(adj + (long)N * CAP);  // 64KB
    unsigned int* xb = (unsigned int*)(Wc + 128 * 256);           // N*64 uints

    init_kernel<<<(N + 255) / 256, 256, 0, stream>>>(cursor, N, flag, spillcnt);
    detect_i64_kernel<<<1, 256, 0, stream>>>(ei, flag);
    xb_kernel<<<(int)(((long)N * 32 + 255) / 256), 256, 0, stream>>>(
        (const float4*)x, (uint2*)xb, (long)N * 32);
    wc_kernel<<<128, 256, 0, stream>>>(Wl, Wr, Wc);
    fill_kernel<<<(E + 255) / 256, 256, 0, stream>>>(ei, cursor, adj, spillcnt, spill,
                                                     flag, E, N);
    gg_kernel<<<(N + 15) / 16, 256, 0, stream>>>(xb, cursor, adj, Wc, bl, out, N);
    spill_kernel<<<64, 256, 0, stream>>>(x, Wl, cursor, spillcnt, spill, out);
}

// Round 3
// 394.453 us; speedup vs baseline: 1.0735x; 1.0112x over previous
//
#include <hip/hip_runtime.h>

#define D_FEAT 128
#define CAP 32
#define SPILLCAP (1 << 18)

typedef short bf16x8 __attribute__((ext_vector_type(8)));
typedef float f32x4 __attribute__((ext_vector_type(4)));

__device__ __forceinline__ unsigned short f2bf(float f) {
    unsigned u = __builtin_bit_cast(unsigned, f);
    u += 0x7FFF + ((u >> 16) & 1);   // round-to-nearest-even
    return (unsigned short)(u >> 16);
}

// ws int layout: [flag:64][cursor:N][spillcnt:64][spill:2*SPILLCAP][adj:N*CAP]
// then Wc[128*256] bf16, xb[N*64] uint (bf16x2)

// ---------------- K0: merged prep: detect i64 + zero cursor + pack Wc ----------------
// block 0: int64 detection (+ spillcnt init); blocks 1..PC: cursor zero;
// blocks PC+1..PC+128: Wc pack. All independent -> one launch.
__global__ __launch_bounds__(256) void prep_kernel(
    const int* __restrict__ ei, int* __restrict__ flag, int* __restrict__ spillcnt,
    int* __restrict__ cursor, int N,
    const float* __restrict__ Wl, const float* __restrict__ Wr,
    unsigned short* __restrict__ Wc, int PC) {
    const int b = blockIdx.x;
    const int t = threadIdx.x;
    if (b == 0) {
        __shared__ int nzs[4];
        int nz = 0;
        for (int i = t; i < 4096; i += 256) nz |= (ei[2 * i + 1] != 0);
        unsigned long long bal = __ballot(nz);
        if ((t & 63) == 0) nzs[t >> 6] = (bal != 0ull) ? 1 : 0;
        __syncthreads();
        if (t == 0) {
            *flag = (nzs[0] | nzs[1] | nzs[2] | nzs[3]) ? 0 : 1;  // 1 = int64 input
            *spillcnt = 0;
        }
    } else if (b <= PC) {
        int gid = (b - 1) * 256 + t;
        if (gid < N) cursor[gid] = 0;
    } else {
        int n = b - PC - 1;  // 0..127
        float w = (t < 128) ? Wl[n * 128 + t] : Wr[n * 128 + (t - 128)];
        Wc[n * 256 + t] = f2bf(w);
    }
}

// ---------------- K1: x -> bf16 ----------------
__global__ void xb_kernel(const float4* __restrict__ x4, uint2* __restrict__ xb2,
                          long total4) {
    long gid = (long)blockIdx.x * blockDim.x + threadIdx.x;
    if (gid >= total4) return;
    float4 v = x4[gid];
    uint2 o;
    o.x = (unsigned)f2bf(v.x) | ((unsigned)f2bf(v.y) << 16);
    o.y = (unsigned)f2bf(v.z) | ((unsigned)f2bf(v.w) << 16);
    xb2[gid] = o;
}

// ---------------- K2: single-pass bucketed CSR fill, 4 edges/thread ----------------
// 4 independent atomic->store chains per thread; int64 edges read as 8B loads.
__global__ __launch_bounds__(256) void fill_kernel(
    const int* __restrict__ ei, int* __restrict__ cursor, int* __restrict__ adj,
    int* __restrict__ spillcnt, int* __restrict__ spill,
    const int* __restrict__ flag, int E, int N) {
    const int is64 = *flag;
    const int base = blockIdx.x * 1024 + threadIdx.x;
    int src[4], dst[4];
#pragma unroll
    for (int j = 0; j < 4; ++j) {
        int e = base + j * 256;
        if (e < E) {
            if (is64) {
                src[j] = (int)((const long long*)ei)[e];
                dst[j] = (int)((const long long*)ei)[(long)E + e];
            } else {
                src[j] = ei[e];
                dst[j] = ei[E + e];
            }
        } else {
            dst[j] = -1;
        }
    }
#pragma unroll
    for (int j = 0; j < 4; ++j) {
        if (dst[j] >= 0) {
            int slot = atomicAdd(&cursor[dst[j]], 1);
            if (slot < CAP) {
                adj[(long)dst[j] * CAP + slot] = src[j];
            } else {
                int sp = atomicAdd(spillcnt, 1);
                if (sp < SPILLCAP) {
                    spill[2 * sp] = src[j];
                    spill[2 * sp + 1] = dst[j];
                }
            }
        }
    }
}

__device__ __forceinline__ void acc_row(float* acc, uint4 v) {
    acc[0] += __builtin_bit_cast(float, v.x << 16);
    acc[1] += __builtin_bit_cast(float, v.x & 0xFFFF0000u);
    acc[2] += __builtin_bit_cast(float, v.y << 16);
    acc[3] += __builtin_bit_cast(float, v.y & 0xFFFF0000u);
    acc[4] += __builtin_bit_cast(float, v.z << 16);
    acc[5] += __builtin_bit_cast(float, v.z & 0xFFFF0000u);
    acc[6] += __builtin_bit_cast(float, v.w << 16);
    acc[7] += __builtin_bit_cast(float, v.w & 0xFFFF0000u);
}

// ---------------- K3: fused gather + MFMA GEMM, 16 nodes per block ----------------
// Quad-per-node: quad qd of wave wv owns node n0+wv*4+qd. 16 lanes x uint4
// = full 256B row per load. All 4 quads' gather chains are independent and
// in flight simultaneously; no cross-quad reduction needed. adj loads are
// unguarded (clamped addr) so they don't wait on the degree load.
__global__ __launch_bounds__(256) void gg_kernel(
    const unsigned int* __restrict__ xb, const int* __restrict__ cursor,
    const int* __restrict__ adj, const unsigned short* __restrict__ Wc,
    const float* __restrict__ bl, float* __restrict__ out, int N) {
    __shared__ __align__(16) unsigned short A[16 * 264];

    const int t = threadIdx.x;
    const int wv = t >> 6;
    const int lane = t & 63;
    const int n0 = blockIdx.x * 16;
    const int fq = lane & 15;   // position within quad
    const int qd = lane >> 4;   // quad id = which of the wave's 4 nodes

    const int n = n0 + wv * 4 + qd;
    const int nc = min(n, N - 1);

    // independent front-loads: degree, adjacency (2x), own rows (4x)
    const int deg = (n < N) ? cursor[n] : 0;
    const int adjv = adj[(long)nc * CAP + fq];
    const int adjv2 = adj[(long)nc * CAP + 16 + fq];

    unsigned xv[4];
#pragma unroll
    for (int q = 0; q < 4; ++q) {
        int nn = n0 + wv * 4 + q;
        xv[q] = (nn < N) ? xb[(long)nn * 64 + lane] : 0u;
    }

    const int cq = min(deg, CAP);
    int mx = max(cq, __shfl_xor(cq, 16));
    mx = max(mx, __shfl_xor(mx, 32));

    float acc[8] = {0.f, 0.f, 0.f, 0.f, 0.f, 0.f, 0.f, 0.f};
    const uint4 z = {0u, 0u, 0u, 0u};
    for (int base = 0; base < mx; base += 4) {
#pragma unroll
        for (int j = 0; j < 4; ++j) {
            int e = base + j;
            int src = __shfl((e < 16) ? adjv : adjv2, qd * 16 + (e & 15));
            uint4 v = (e < cq) ? *(const uint4*)&xb[(long)src * 64 + fq * 4] : z;
            acc_row(acc, v);
        }
    }

    const float iv = 1.0f / (float)max(deg, 1);
    uint4 o;
    o.x = (unsigned)f2bf(acc[0] * iv) | ((unsigned)f2bf(acc[1] * iv) << 16);
    o.y = (unsigned)f2bf(acc[2] * iv) | ((unsigned)f2bf(acc[3] * iv) << 16);
    o.z = (unsigned)f2bf(acc[4] * iv) | ((unsigned)f2bf(acc[5] * iv) << 16);
    o.w = (unsigned)f2bf(acc[6] * iv) | ((unsigned)f2bf(acc[7] * iv) << 16);
    *(uint4*)&A[(wv * 4 + qd) * 264 + fq * 8] = o;
#pragma unroll
    for (int q = 0; q < 4; ++q)
        *(unsigned*)&A[(wv * 4 + q) * 264 + 128 + 2 * lane] = xv[q];
    __syncthreads();

    // phase 2: MFMA — wave w computes cols [w*32, w*32+32)
    const int l15 = lane & 15;
    const int quad = lane >> 4;
    f32x4 acc2[2];
    acc2[0] = (f32x4){0.f, 0.f, 0.f, 0.f};
    acc2[1] = (f32x4){0.f, 0.f, 0.f, 0.f};

#pragma unroll
    for (int kc = 0; kc < 8; ++kc) {
        const int k0 = kc * 32;
        bf16x8 af = *(const bf16x8*)&A[l15 * 264 + k0 + quad * 8];
#pragma unroll
        for (int nt = 0; nt < 2; ++nt) {
            int col = wv * 32 + nt * 16 + l15;
            bf16x8 bf = *(const bf16x8*)&Wc[col * 256 + k0 + quad * 8];
            acc2[nt] = __builtin_amdgcn_mfma_f32_16x16x32_bf16(af, bf, acc2[nt], 0, 0, 0);
        }
    }

    // epilogue: C/D layout col=lane&15, row=quad*4+reg
#pragma unroll
    for (int nt = 0; nt < 2; ++nt) {
        int col = wv * 32 + nt * 16 + l15;
        float bias = bl[col];
#pragma unroll
        for (int r = 0; r < 4; ++r) {
            int node = n0 + quad * 4 + r;
            if (node < N) out[(long)node * 128 + col] = acc2[nt][r] + bias;
        }
    }
}

// ---------------- K4: exact spill fixup (normally ~0 iterations) ----------------
// For each spilled edge: out[dst][c] += (Wl[c] . x[src]) / deg[dst], in f32.
__global__ __launch_bounds__(256) void spill_kernel(
    const float* __restrict__ x, const float* __restrict__ Wl,
    const int* __restrict__ cursor, const int* __restrict__ spillcnt,
    const int* __restrict__ spill, float* __restrict__ out) {
    const int wv = threadIdx.x >> 6;
    const int lane = threadIdx.x & 63;
    const int sc = min(*spillcnt, SPILLCAP);
    for (int i = blockIdx.x * 4 + wv; i < sc; i += gridDim.x * 4) {
        int src = spill[2 * i];
        int dst = spill[2 * i + 1];
        float inv = 1.0f / (float)max(cursor[dst], 1);
#pragma unroll
        for (int cc = 0; cc < 2; ++cc) {
            int c = lane + cc * 64;
            float s = 0.0f;
            for (int k = 0; k < 128; k += 4) {
                float4 w4 = *(const float4*)&Wl[c * 128 + k];
                float4 x4 = *(const float4*)&x[(long)src * 128 + k];
                s += w4.x * x4.x + w4.y * x4.y + w4.z * x4.z + w4.w * x4.w;
            }
            atomicAdd(&out[(long)dst * 128 + c], s * inv);
        }
    }
}

extern "C" void kernel_launch(void* const* d_in, const int* in_sizes, int n_in,
                              void* d_out, int out_size, void* d_ws, size_t ws_size,
                              hipStream_t stream) {
    const float* x = (const float*)d_in[0];
    const int* ei = (const int*)d_in[1];
    const float* Wl = (const float*)d_in[2];
    const float* bl = (const float*)d_in[3];
    const float* Wr = (const float*)d_in[4];
    float* out = (float*)d_out;

    const int N = in_sizes[0] / D_FEAT;  // 100000
    const int E = in_sizes[1] / 2;       // 1600000

    int* wsI = (int*)d_ws;
    int* flag = wsI;                         // 64
    int* cursor = flag + 64;                 // N (degree after fill)
    int* spillcnt = cursor + N;              // 64
    int* spill = spillcnt + 64;              // 2*SPILLCAP
    int* adj = spill + 2 * SPILLCAP;         // N*CAP
    unsigned short* Wc = (unsigned short*)(adj + (long)N * CAP);  // 64KB
    unsigned int* xb = (unsigned int*)(Wc + 128 * 256);           // N*64 uints

    const int PC = (N + 255) / 256;  // cursor-zero blocks

    prep_kernel<<<1 + PC + 128, 256, 0, stream>>>(ei, flag, spillcnt, cursor, N,
                                                  Wl, Wr, Wc, PC);
    xb_kernel<<<(int)(((long)N * 32 + 255) / 256), 256, 0, stream>>>(
        (const float4*)x, (uint2*)xb, (long)N * 32);
    fill_kernel<<<(E + 1023) / 1024, 256, 0, stream>>>(ei, cursor, adj, spillcnt,
                                                       spill, flag, E, N);
    gg_kernel<<<(N + 15) / 16, 256, 0, stream>>>(xb, cursor, adj, Wc, bl, out, N);
    spill_kernel<<<64, 256, 0, stream>>>(x, Wl, cursor, spillcnt, spill, out);
}

// Round 4
// 334.094 us; speedup vs baseline: 1.2674x; 1.1807x over previous
//
#include <hip/hip_runtime.h>

#define D_FEAT 128
#define CAP 32
#define SPILLCAP (1 << 18)

typedef short bf16x8 __attribute__((ext_vector_type(8)));
typedef float f32x4 __attribute__((ext_vector_type(4)));

__device__ __forceinline__ unsigned short f2bf(float f) {
    unsigned u = __builtin_bit_cast(unsigned, f);
    u += 0x7FFF + ((u >> 16) & 1);   // round-to-nearest-even
    return (unsigned short)(u >> 16);
}

// ws int layout: [flag:64][cursor:N][spillcnt:64][spill:2*SPILLCAP][adj:N*CAP]
// then Wc[128*256] bf16, xb[N*64] uint (bf16x2)

// ---------------- K0: merged prep: detect i64 + zero cursor + pack Wc + x->bf16 ----
// block 0: int64 detect (+spillcnt); 1..PC: cursor zero; PC+1..PC+128: Wc pack;
// rest: xb conversion. All independent -> one launch.
__global__ __launch_bounds__(256) void prep_kernel(
    const int* __restrict__ ei, int* __restrict__ flag, int* __restrict__ spillcnt,
    int* __restrict__ cursor, int N,
    const float* __restrict__ Wl, const float* __restrict__ Wr,
    unsigned short* __restrict__ Wc,
    const float4* __restrict__ x4, uint2* __restrict__ xb2, long total4, int PC) {
    const int b = blockIdx.x;
    const int t = threadIdx.x;
    if (b == 0) {
        __shared__ int nzs[4];
        int nz = 0;
        for (int i = t; i < 4096; i += 256) nz |= (ei[2 * i + 1] != 0);
        unsigned long long bal = __ballot(nz);
        if ((t & 63) == 0) nzs[t >> 6] = (bal != 0ull) ? 1 : 0;
        __syncthreads();
        if (t == 0) {
            *flag = (nzs[0] | nzs[1] | nzs[2] | nzs[3]) ? 0 : 1;  // 1 = int64 input
            *spillcnt = 0;
        }
    } else if (b <= PC) {
        int gid = (b - 1) * 256 + t;
        if (gid < N) cursor[gid] = 0;
    } else if (b <= PC + 128) {
        int n = b - PC - 1;  // 0..127
        float w = (t < 128) ? Wl[n * 128 + t] : Wr[n * 128 + (t - 128)];
        Wc[n * 256 + t] = f2bf(w);
    } else {
        long gid = (long)(b - PC - 129) * 256 + t;
        if (gid < total4) {
            float4 v = x4[gid];
            uint2 o;
            o.x = (unsigned)f2bf(v.x) | ((unsigned)f2bf(v.y) << 16);
            o.y = (unsigned)f2bf(v.z) | ((unsigned)f2bf(v.w) << 16);
            xb2[gid] = o;
        }
    }
}

// ---------------- K1: single-pass bucketed CSR fill, 8 edges/thread ----------------
// 8 independent atomic->store chains per thread; int64 edges read as 8B loads.
__global__ __launch_bounds__(256) void fill_kernel(
    const int* __restrict__ ei, int* __restrict__ cursor, int* __restrict__ adj,
    int* __restrict__ spillcnt, int* __restrict__ spill,
    const int* __restrict__ flag, int E, int N) {
    const int is64 = *flag;
    const int base = blockIdx.x * 2048 + threadIdx.x;
    int src[8], dst[8];
#pragma unroll
    for (int j = 0; j < 8; ++j) {
        int e = base + j * 256;
        if (e < E) {
            if (is64) {
                src[j] = (int)((const long long*)ei)[e];
                dst[j] = (int)((const long long*)ei)[(long)E + e];
            } else {
                src[j] = ei[e];
                dst[j] = ei[E + e];
            }
        } else {
            dst[j] = -1;
        }
    }
#pragma unroll
    for (int j = 0; j < 8; ++j) {
        if (dst[j] >= 0) {
            int slot = atomicAdd(&cursor[dst[j]], 1);
            if (slot < CAP) {
                adj[(long)dst[j] * CAP + slot] = src[j];
            } else {
                int sp = atomicAdd(spillcnt, 1);
                if (sp < SPILLCAP) {
                    spill[2 * sp] = src[j];
                    spill[2 * sp + 1] = dst[j];
                }
            }
        }
    }
}

__device__ __forceinline__ void acc_row(float* acc, uint4 v) {
    acc[0] += __builtin_bit_cast(float, v.x << 16);
    acc[1] += __builtin_bit_cast(float, v.x & 0xFFFF0000u);
    acc[2] += __builtin_bit_cast(float, v.y << 16);
    acc[3] += __builtin_bit_cast(float, v.y & 0xFFFF0000u);
    acc[4] += __builtin_bit_cast(float, v.z << 16);
    acc[5] += __builtin_bit_cast(float, v.z & 0xFFFF0000u);
    acc[6] += __builtin_bit_cast(float, v.w << 16);
    acc[7] += __builtin_bit_cast(float, v.w & 0xFFFF0000u);
}

// src for edge e of this quad's node; e >= cq redirects to row 0 (L1-hot).
__device__ __forceinline__ int pick_src(int adjv, int adjv2, int e, int cq, int qd) {
    int ec = e & 31;
    int s = __shfl((ec < 16) ? adjv : adjv2, qd * 16 + (ec & 15));
    return (e < cq) ? s : 0;
}

// ---------------- K2: fused gather + MFMA GEMM, 16 nodes per block ----------------
// Quad-per-node + 2-stage software pipeline: 8 uint4 row-loads in flight per
// wave (2 chunks x 4 quads). Loads are UNCONDITIONAL with clamped/redirected
// addresses (no exec-mask branches on the load path); predication happens at
// the accumulate step only.
__global__ __launch_bounds__(256) void gg_kernel(
    const unsigned int* __restrict__ xb, const int* __restrict__ cursor,
    const int* __restrict__ adj, const unsigned short* __restrict__ Wc,
    const float* __restrict__ bl, float* __restrict__ out, int N) {
    __shared__ __align__(16) unsigned short A[16 * 264];

    const int t = threadIdx.x;
    const int wv = t >> 6;
    const int lane = t & 63;
    const int n0 = blockIdx.x * 16;
    const int fq = lane & 15;   // position within quad
    const int qd = lane >> 4;   // quad id = which of the wave's 4 nodes

    const int n = n0 + wv * 4 + qd;
    const int nc = min(n, N - 1);

    // independent front-loads: degree, adjacency (2x), own rows (4x)
    const int deg = (n < N) ? cursor[n] : 0;
    int adjv = adj[(long)nc * CAP + fq];
    int adjv2 = adj[(long)nc * CAP + 16 + fq];

    unsigned xv[4];
#pragma unroll
    for (int q = 0; q < 4; ++q) {
        int nn = n0 + wv * 4 + q;
        xv[q] = (nn < N) ? xb[(long)nn * 64 + lane] : 0u;
    }

    // clamp stored srcs (entries beyond deg are uninitialized garbage)
    adjv = min(max(adjv, 0), N - 1);
    adjv2 = min(max(adjv2, 0), N - 1);

    const int cq = min(deg, CAP);
    int mx = max(cq, __shfl_xor(cq, 16));
    mx = max(mx, __shfl_xor(mx, 32));
    mx = (mx + 3) & ~3;  // pad to chunk of 4

    float acc[8] = {0.f, 0.f, 0.f, 0.f, 0.f, 0.f, 0.f, 0.f};
    uint4 va[4], vb[4];
    // prefetch chunk 0
#pragma unroll
    for (int j = 0; j < 4; ++j) {
        int s = pick_src(adjv, adjv2, j, cq, qd);
        va[j] = *(const uint4*)&xb[(long)s * 64 + fq * 4];
    }
    for (int base = 0; base < mx; base += 4) {
        // issue next chunk's 4 loads before consuming current chunk
#pragma unroll
        for (int j = 0; j < 4; ++j) {
            int s = pick_src(adjv, adjv2, base + 4 + j, cq, qd);
            vb[j] = *(const uint4*)&xb[(long)s * 64 + fq * 4];
        }
#pragma unroll
        for (int j = 0; j < 4; ++j) {
            if (base + j < cq) acc_row(acc, va[j]);
        }
#pragma unroll
        for (int j = 0; j < 4; ++j) va[j] = vb[j];
    }

    const float iv = 1.0f / (float)max(deg, 1);
    uint4 o;
    o.x = (unsigned)f2bf(acc[0] * iv) | ((unsigned)f2bf(acc[1] * iv) << 16);
    o.y = (unsigned)f2bf(acc[2] * iv) | ((unsigned)f2bf(acc[3] * iv) << 16);
    o.z = (unsigned)f2bf(acc[4] * iv) | ((unsigned)f2bf(acc[5] * iv) << 16);
    o.w = (unsigned)f2bf(acc[6] * iv) | ((unsigned)f2bf(acc[7] * iv) << 16);
    *(uint4*)&A[(wv * 4 + qd) * 264 + fq * 8] = o;
#pragma unroll
    for (int q = 0; q < 4; ++q)
        *(unsigned*)&A[(wv * 4 + q) * 264 + 128 + 2 * lane] = xv[q];
    __syncthreads();

    // phase 2: MFMA — wave w computes cols [w*32, w*32+32)
    const int l15 = lane & 15;
    const int quad = lane >> 4;
    f32x4 acc2[2];
    acc2[0] = (f32x4){0.f, 0.f, 0.f, 0.f};
    acc2[1] = (f32x4){0.f, 0.f, 0.f, 0.f};

#pragma unroll
    for (int kc = 0; kc < 8; ++kc) {
        const int k0 = kc * 32;
        bf16x8 af = *(const bf16x8*)&A[l15 * 264 + k0 + quad * 8];
#pragma unroll
        for (int nt = 0; nt < 2; ++nt) {
            int col = wv * 32 + nt * 16 + l15;
            bf16x8 bf = *(const bf16x8*)&Wc[col * 256 + k0 + quad * 8];
            acc2[nt] = __builtin_amdgcn_mfma_f32_16x16x32_bf16(af, bf, acc2[nt], 0, 0, 0);
        }
    }

    // epilogue: C/D layout col=lane&15, row=quad*4+reg
#pragma unroll
    for (int nt = 0; nt < 2; ++nt) {
        int col = wv * 32 + nt * 16 + l15;
        float bias = bl[col];
#pragma unroll
        for (int r = 0; r < 4; ++r) {
            int node = n0 + quad * 4 + r;
            if (node < N) out[(long)node * 128 + col] = acc2[nt][r] + bias;
        }
    }
}

// ---------------- K3: exact spill fixup (normally ~0 iterations) ----------------
// For each spilled edge: out[dst][c] += (Wl[c] . x[src]) / deg[dst], in f32.
__global__ __launch_bounds__(256) void spill_kernel(
    const float* __restrict__ x, const float* __restrict__ Wl,
    const int* __restrict__ cursor, const int* __restrict__ spillcnt,
    const int* __restrict__ spill, float* __restrict__ out) {
    const int wv = threadIdx.x >> 6;
    const int lane = threadIdx.x & 63;
    const int sc = min(*spillcnt, SPILLCAP);
    for (int i = blockIdx.x * 4 + wv; i < sc; i += gridDim.x * 4) {
        int src = spill[2 * i];
        int dst = spill[2 * i + 1];
        float inv = 1.0f / (float)max(cursor[dst], 1);
#pragma unroll
        for (int cc = 0; cc < 2; ++cc) {
            int c = lane + cc * 64;
            float s = 0.0f;
            for (int k = 0; k < 128; k += 4) {
                float4 w4 = *(const float4*)&Wl[c * 128 + k];
                float4 x4 = *(const float4*)&x[(long)src * 128 + k];
                s += w4.x * x4.x + w4.y * x4.y + w4.z * x4.z + w4.w * x4.w;
            }
            atomicAdd(&out[(long)dst * 128 + c], s * inv);
        }
    }
}

extern "C" void kernel_launch(void* const* d_in, const int* in_sizes, int n_in,
                              void* d_out, int out_size, void* d_ws, size_t ws_size,
                              hipStream_t stream) {
    const float* x = (const float*)d_in[0];
    const int* ei = (const int*)d_in[1];
    const float* Wl = (const float*)d_in[2];
    const float* bl = (const float*)d_in[3];
    const float* Wr = (const float*)d_in[4];
    float* out = (float*)d_out;

    const int N = in_sizes[0] / D_FEAT;  // 100000
    const int E = in_sizes[1] / 2;       // 1600000

    int* wsI = (int*)d_ws;
    int* flag = wsI;                         // 64
    int* cursor = flag + 64;                 // N (degree after fill)
    int* spillcnt = cursor + N;              // 64
    int* spill = spillcnt + 64;              // 2*SPILLCAP
    int* adj = spill + 2 * SPILLCAP;         // N*CAP
    unsigned short* Wc = (unsigned short*)(adj + (long)N * CAP);  // 64KB
    unsigned int* xb = (unsigned int*)(Wc + 128 * 256);           // N*64 uints

    const long total4 = (long)N * 32;
    const int PC = (N + 255) / 256;                    // cursor-zero blocks
    const int XBB = (int)((total4 + 255) / 256);       // xb blocks

    prep_kernel<<<1 + PC + 128 + XBB, 256, 0, stream>>>(
        ei, flag, spillcnt, cursor, N, Wl, Wr, Wc, (const float4*)x, (uint2*)xb,
        total4, PC);
    fill_kernel<<<(E + 2047) / 2048, 256, 0, stream>>>(ei, cursor, adj, spillcnt,
                                                       spill, flag, E, N);
    gg_kernel<<<(N + 15) / 16, 256, 0, stream>>>(xb, cursor, adj, Wc, bl, out, N);
    spill_kernel<<<64, 256, 0, stream>>>(x, Wl, cursor, spillcnt, spill, out);
}

// Round 5
// 290.271 us; speedup vs baseline: 1.4587x; 1.1510x over previous
//
#include <hip/hip_runtime.h>

#define D_FEAT 128
#define CAP 32
#define S1CAP (1 << 16)
#define S2CAP (1 << 16)
#define LOGB 7
#define LOCB 128
#define BCAP 2560
#define CHUNK 16384
#define NBUK_MAX 1024

typedef short bf16x8 __attribute__((ext_vector_type(8)));
typedef float f32x4 __attribute__((ext_vector_type(4)));

__device__ __forceinline__ unsigned short f2bf(float f) {
    unsigned u = __builtin_bit_cast(unsigned, f);
    u += 0x7FFF + ((u >> 16) & 1);   // round-to-nearest-even
    return (unsigned short)(u >> 16);
}

// ws int layout: [flag:64][cursor:N][s1cnt:64][spill1:2*S1CAP][s2cnt:64]
// [spill2:2*S2CAP][bincnt:NBUK_MAX][bins:NBUK*BCAP][adj:N*CAP]
// then Wc[128*256] bf16, xb[N*64] uint (bf16x2)

// ---------------- K0: merged prep: detect i64 + zero counters + Wc + x->bf16 ----
__global__ __launch_bounds__(256) void prep_kernel(
    const int* __restrict__ ei, int* __restrict__ flag, int* __restrict__ s1cnt,
    int* __restrict__ s2cnt, int* __restrict__ bincnt, int NBUK,
    const float* __restrict__ Wl, const float* __restrict__ Wr,
    unsigned short* __restrict__ Wc,
    const float4* __restrict__ x4, uint2* __restrict__ xb2, long total4) {
    const int b = blockIdx.x;
    const int t = threadIdx.x;
    if (b == 0) {
        __shared__ int nzs[4];
        int nz = 0;
        for (int i = t; i < 4096; i += 256) nz |= (ei[2 * i + 1] != 0);
        unsigned long long bal = __ballot(nz);
        if ((t & 63) == 0) nzs[t >> 6] = (bal != 0ull) ? 1 : 0;
        __syncthreads();
        if (t == 0) {
            *flag = (nzs[0] | nzs[1] | nzs[2] | nzs[3]) ? 0 : 1;  // 1 = int64 input
            *s1cnt = 0;
            *s2cnt = 0;
        }
        for (int i = t; i < NBUK; i += 256) bincnt[i] = 0;
    } else if (b <= 128) {
        int n = b - 1;  // 0..127
        float w = (t < 128) ? Wl[n * 128 + t] : Wr[n * 128 + (t - 128)];
        Wc[n * 256 + t] = f2bf(w);
    } else {
        long gid = (long)(b - 129) * 256 + t;
        if (gid < total4) {
            float4 v = x4[gid];
            uint2 o;
            o.x = (unsigned)f2bf(v.x) | ((unsigned)f2bf(v.y) << 16);
            o.y = (unsigned)f2bf(v.z) | ((unsigned)f2bf(v.w) << 16);
            xb2[gid] = o;
        }
    }
}

// ---------------- K1: bin pass — LDS histogram + range reserve + scatter ----------
// Bucket = dst>>LOGB (LOCB nodes). Packed entry: (dst&127)<<25 | src.
__global__ __launch_bounds__(256) void bin_kernel(
    const int* __restrict__ ei, const int* __restrict__ flag,
    int* __restrict__ bincnt, unsigned* __restrict__ bins,
    int* __restrict__ s1cnt, int* __restrict__ spill1, int E, int N, int NBUK) {
    __shared__ int hist[NBUK_MAX];
    __shared__ int rbase[NBUK_MAX];
    const int t = threadIdx.x;
    const long e0 = (long)blockIdx.x * CHUNK;
    const int cnt = (int)min((long)CHUNK, (long)E - e0);
    const int is64 = *flag;

    for (int i = t; i < NBUK; i += 256) hist[i] = 0;
    __syncthreads();

    // phase A: histogram dst buckets
    for (int i = t; i < cnt; i += 256) {
        long e = e0 + i;
        int dst = is64 ? (int)((const long long*)ei)[(long)E + e] : ei[(long)E + e];
        dst = min(max(dst, 0), N - 1);
        atomicAdd(&hist[dst >> LOGB], 1);
    }
    __syncthreads();

    // phase B: reserve contiguous ranges (one global atomic per nonempty bucket)
    for (int i = t; i < NBUK; i += 256) {
        int h = hist[i];
        rbase[i] = (h > 0) ? atomicAdd(&bincnt[i], h) : 0;
        hist[i] = 0;  // reuse as bump counter
    }
    __syncthreads();

    // phase C: scatter packed entries
    for (int i = t; i < cnt; i += 256) {
        long e = e0 + i;
        int src, dst;
        if (is64) {
            src = (int)((const long long*)ei)[e];
            dst = (int)((const long long*)ei)[(long)E + e];
        } else {
            src = ei[e];
            dst = ei[(long)E + e];
        }
        src = min(max(src, 0), N - 1);
        dst = min(max(dst, 0), N - 1);
        int bk = dst >> LOGB;
        int slot = rbase[bk] + atomicAdd(&hist[bk], 1);
        if (slot < BCAP) {
            bins[(long)bk * BCAP + slot] = ((unsigned)(dst & (LOCB - 1)) << 25) | (unsigned)src;
        } else {
            int sp = atomicAdd(s1cnt, 1);
            if (sp < S1CAP) {
                spill1[2 * sp] = src;
                spill1[2 * sp + 1] = dst;
            }
        }
    }
}

// ---------------- K2: per-bucket CSR fill — LDS cursors, no global atomics -------
__global__ __launch_bounds__(256) void fill2_kernel(
    const unsigned* __restrict__ bins, const int* __restrict__ bincnt,
    int* __restrict__ adj, int* __restrict__ cursor,
    int* __restrict__ s2cnt, int* __restrict__ spill2, int N) {
    __shared__ int cur[LOCB];
    const int bk = blockIdx.x;
    const int t = threadIdx.x;
    if (t < LOCB) cur[t] = 0;
    __syncthreads();
    const int cnt = min(bincnt[bk], BCAP);
    const int nb = bk << LOGB;
    for (int i = t; i < cnt; i += 256) {
        unsigned v = bins[(long)bk * BCAP + i];
        int src = (int)(v & 0x1FFFFFFu);
        int ld = (int)(v >> 25);
        int slot = atomicAdd(&cur[ld], 1);
        int dst = nb + ld;
        if (slot < CAP) {
            adj[(long)dst * CAP + slot] = src;
        } else {
            int sp = atomicAdd(s2cnt, 1);
            if (sp < S2CAP) {
                spill2[2 * sp] = src;
                spill2[2 * sp + 1] = dst;
            }
        }
    }
    __syncthreads();
    if (t < LOCB && nb + t < N) cursor[nb + t] = cur[t];
}

// ---------------- K3: bucket-overflow fill (normally 0 edges) --------------------
__global__ __launch_bounds__(256) void spillfill_kernel(
    const int* __restrict__ s1cnt, const int* __restrict__ spill1,
    int* __restrict__ cursor, int* __restrict__ adj,
    int* __restrict__ s2cnt, int* __restrict__ spill2) {
    const int sc = min(*s1cnt, S1CAP);
    for (int i = blockIdx.x * 256 + threadIdx.x; i < sc; i += gridDim.x * 256) {
        int src = spill1[2 * i];
        int dst = spill1[2 * i + 1];
        int slot = atomicAdd(&cursor[dst], 1);
        if (slot < CAP) {
            adj[(long)dst * CAP + slot] = src;
        } else {
            int sp = atomicAdd(s2cnt, 1);
            if (sp < S2CAP) {
                spill2[2 * sp] = src;
                spill2[2 * sp + 1] = dst;
            }
        }
    }
}

__device__ __forceinline__ void acc_row(float* acc, uint4 v) {
    acc[0] += __builtin_bit_cast(float, v.x << 16);
    acc[1] += __builtin_bit_cast(float, v.x & 0xFFFF0000u);
    acc[2] += __builtin_bit_cast(float, v.y << 16);
    acc[3] += __builtin_bit_cast(float, v.y & 0xFFFF0000u);
    acc[4] += __builtin_bit_cast(float, v.z << 16);
    acc[5] += __builtin_bit_cast(float, v.z & 0xFFFF0000u);
    acc[6] += __builtin_bit_cast(float, v.w << 16);
    acc[7] += __builtin_bit_cast(float, v.w & 0xFFFF0000u);
}

// src for edge e of this quad's node; e >= cq redirects to row 0 (L1-hot).
__device__ __forceinline__ int pick_src(int adjv, int adjv2, int e, int cq, int qd) {
    int ec = e & 31;
    int s = __shfl((ec < 16) ? adjv : adjv2, qd * 16 + (ec & 15));
    return (e < cq) ? s : 0;
}

// ---------------- K4: fused gather + MFMA GEMM, 16 nodes per block ----------------
__global__ __launch_bounds__(256) void gg_kernel(
    const unsigned int* __restrict__ xb, const int* __restrict__ cursor,
    const int* __restrict__ adj, const unsigned short* __restrict__ Wc,
    const float* __restrict__ bl, float* __restrict__ out, int N) {
    __shared__ __align__(16) unsigned short A[16 * 264];

    const int t = threadIdx.x;
    const int wv = t >> 6;
    const int lane = t & 63;
    const int n0 = blockIdx.x * 16;
    const int fq = lane & 15;   // position within quad
    const int qd = lane >> 4;   // quad id = which of the wave's 4 nodes

    const int n = n0 + wv * 4 + qd;
    const int nc = min(n, N - 1);

    // independent front-loads: degree, adjacency (2x), own rows (4x)
    const int deg = (n < N) ? cursor[n] : 0;
    int adjv = adj[(long)nc * CAP + fq];
    int adjv2 = adj[(long)nc * CAP + 16 + fq];

    unsigned xv[4];
#pragma unroll
    for (int q = 0; q < 4; ++q) {
        int nn = n0 + wv * 4 + q;
        xv[q] = (nn < N) ? xb[(long)nn * 64 + lane] : 0u;
    }

    // clamp stored srcs (entries beyond deg are uninitialized garbage)
    adjv = min(max(adjv, 0), N - 1);
    adjv2 = min(max(adjv2, 0), N - 1);

    const int cq = min(deg, CAP);
    int mx = max(cq, __shfl_xor(cq, 16));
    mx = max(mx, __shfl_xor(mx, 32));
    mx = (mx + 3) & ~3;  // pad to chunk of 4

    float acc[8] = {0.f, 0.f, 0.f, 0.f, 0.f, 0.f, 0.f, 0.f};
    uint4 va[4], vb[4];
    // prefetch chunk 0
#pragma unroll
    for (int j = 0; j < 4; ++j) {
        int s = pick_src(adjv, adjv2, j, cq, qd);
        va[j] = *(const uint4*)&xb[(long)s * 64 + fq * 4];
    }
    for (int base = 0; base < mx; base += 4) {
        // issue next chunk's 4 loads before consuming current chunk
#pragma unroll
        for (int j = 0; j < 4; ++j) {
            int s = pick_src(adjv, adjv2, base + 4 + j, cq, qd);
            vb[j] = *(const uint4*)&xb[(long)s * 64 + fq * 4];
        }
#pragma unroll
        for (int j = 0; j < 4; ++j) {
            if (base + j < cq) acc_row(acc, va[j]);
        }
#pragma unroll
        for (int j = 0; j < 4; ++j) va[j] = vb[j];
    }

    const float iv = 1.0f / (float)max(deg, 1);
    uint4 o;
    o.x = (unsigned)f2bf(acc[0] * iv) | ((unsigned)f2bf(acc[1] * iv) << 16);
    o.y = (unsigned)f2bf(acc[2] * iv) | ((unsigned)f2bf(acc[3] * iv) << 16);
    o.z = (unsigned)f2bf(acc[4] * iv) | ((unsigned)f2bf(acc[5] * iv) << 16);
    o.w = (unsigned)f2bf(acc[6] * iv) | ((unsigned)f2bf(acc[7] * iv) << 16);
    *(uint4*)&A[(wv * 4 + qd) * 264 + fq * 8] = o;
#pragma unroll
    for (int q = 0; q < 4; ++q)
        *(unsigned*)&A[(wv * 4 + q) * 264 + 128 + 2 * lane] = xv[q];
    __syncthreads();

    // phase 2: MFMA — wave w computes cols [w*32, w*32+32)
    const int l15 = lane & 15;
    const int quad = lane >> 4;
    f32x4 acc2[2];
    acc2[0] = (f32x4){0.f, 0.f, 0.f, 0.f};
    acc2[1] = (f32x4){0.f, 0.f, 0.f, 0.f};

#pragma unroll
    for (int kc = 0; kc < 8; ++kc) {
        const int k0 = kc * 32;
        bf16x8 af = *(const bf16x8*)&A[l15 * 264 + k0 + quad * 8];
#pragma unroll
        for (int nt = 0; nt < 2; ++nt) {
            int col = wv * 32 + nt * 16 + l15;
            bf16x8 bf = *(const bf16x8*)&Wc[col * 256 + k0 + quad * 8];
            acc2[nt] = __builtin_amdgcn_mfma_f32_16x16x32_bf16(af, bf, acc2[nt], 0, 0, 0);
        }
    }

    // epilogue: C/D layout col=lane&15, row=quad*4+reg
#pragma unroll
    for (int nt = 0; nt < 2; ++nt) {
        int col = wv * 32 + nt * 16 + l15;
        float bias = bl[col];
#pragma unroll
        for (int r = 0; r < 4; ++r) {
            int node = n0 + quad * 4 + r;
            if (node < N) out[(long)node * 128 + col] = acc2[nt][r] + bias;
        }
    }
}

// ---------------- K5: exact CAP-overflow fixup (normally ~0 iterations) ----------
// For each spilled edge: out[dst][c] += (Wl[c] . x[src]) / deg[dst], in f32.
__global__ __launch_bounds__(256) void spill2_kernel(
    const float* __restrict__ x, const float* __restrict__ Wl,
    const int* __restrict__ cursor, const int* __restrict__ s2cnt,
    const int* __restrict__ spill2, float* __restrict__ out) {
    const int wv = threadIdx.x >> 6;
    const int lane = threadIdx.x & 63;
    const int sc = min(*s2cnt, S2CAP);
    for (int i = blockIdx.x * 4 + wv; i < sc; i += gridDim.x * 4) {
        int src = spill2[2 * i];
        int dst = spill2[2 * i + 1];
        float inv = 1.0f / (float)max(cursor[dst], 1);
#pragma unroll
        for (int cc = 0; cc < 2; ++cc) {
            int c = lane + cc * 64;
            float s = 0.0f;
            for (int k = 0; k < 128; k += 4) {
                float4 w4 = *(const float4*)&Wl[c * 128 + k];
                float4 x4 = *(const float4*)&x[(long)src * 128 + k];
                s += w4.x * x4.x + w4.y * x4.y + w4.z * x4.z + w4.w * x4.w;
            }
            atomicAdd(&out[(long)dst * 128 + c], s * inv);
        }
    }
}

extern "C" void kernel_launch(void* const* d_in, const int* in_sizes, int n_in,
                              void* d_out, int out_size, void* d_ws, size_t ws_size,
                              hipStream_t stream) {
    const float* x = (const float*)d_in[0];
    const int* ei = (const int*)d_in[1];
    const float* Wl = (const float*)d_in[2];
    const float* bl = (const float*)d_in[3];
    const float* Wr = (const float*)d_in[4];
    float* out = (float*)d_out;

    const int N = in_sizes[0] / D_FEAT;  // 100000
    const int E = in_sizes[1] / 2;       // 1600000
    const int NBUK = (N + LOCB - 1) >> LOGB;  // 782 (must be <= NBUK_MAX)

    int* wsI = (int*)d_ws;
    int* flag = wsI;                          // 64
    int* cursor = flag + 64;                  // N (degree after fill)
    int* s1cnt = cursor + N;                  // 64
    int* spill1 = s1cnt + 64;                 // 2*S1CAP
    int* s2cnt = spill1 + 2 * S1CAP;          // 64
    int* spill2 = s2cnt + 64;                 // 2*S2CAP
    int* bincnt = spill2 + 2 * S2CAP;         // NBUK_MAX
    unsigned* bins = (unsigned*)(bincnt + NBUK_MAX);              // NBUK*BCAP
    int* adj = (int*)(bins + (long)NBUK * BCAP);                  // N*CAP
    unsigned short* Wc = (unsigned short*)(adj + (long)N * CAP);  // 64KB
    unsigned int* xb = (unsigned int*)(Wc + 128 * 256);           // N*64 uints

    const long total4 = (long)N * 32;
    const int XBB = (int)((total4 + 255) / 256);

    prep_kernel<<<1 + 128 + XBB, 256, 0, stream>>>(ei, flag, s1cnt, s2cnt, bincnt,
                                                   NBUK, Wl, Wr, Wc,
                                                   (const float4*)x, (uint2*)xb, total4);
    bin_kernel<<<(E + CHUNK - 1) / CHUNK, 256, 0, stream>>>(ei, flag, bincnt, bins,
                                                            s1cnt, spill1, E, N, NBUK);
    fill2_kernel<<<NBUK, 256, 0, stream>>>(bins, bincnt, adj, cursor, s2cnt, spill2, N);
    spillfill_kernel<<<64, 256, 0, stream>>>(s1cnt, spill1, cursor, adj, s2cnt, spill2);
    gg_kernel<<<(N + 15) / 16, 256, 0, stream>>>(xb, cursor, adj, Wc, bl, out, N);
    spill2_kernel<<<64, 256, 0, stream>>>(x, Wl, cursor, s2cnt, spill2, out);
}

// Round 7
// 261.445 us; speedup vs baseline: 1.6196x; 1.1103x over previous
//
#include <hip/hip_runtime.h>

#define D_FEAT 128
#define CAP 32
#define S1CAP (1 << 16)
#define S2CAP (1 << 16)
#define LOGB 7
#define LOCB 128
#define BCAP 2560
#define CHUNK 8192
#define NBUK_MAX 1024
#define BPAD 8

typedef short bf16x8 __attribute__((ext_vector_type(8)));
typedef float f32x4 __attribute__((ext_vector_type(4)));

__device__ __forceinline__ unsigned short f2bf(float f) {
    unsigned u = __builtin_bit_cast(unsigned, f);
    u += 0x7FFF + ((u >> 16) & 1);   // round-to-nearest-even
    return (unsigned short)(u >> 16);
}

// ws int layout: [flag:64][cursor:N][s1cnt:64][spill1:2*S1CAP][s2cnt:64]
// [spill2:2*S2CAP][bincnt:NBUK_MAX*BPAD][bins:NBUK*BCAP][adj:N*CAP]
// then Wc[128*256] bf16, xb[N*64] uint (bf16x2)

// ---------------- K0: tiny prep: detect i64 + zero counters (8 blocks) ----------
__global__ __launch_bounds__(256) void tprep_kernel(
    const int* __restrict__ ei, int* __restrict__ flag, int* __restrict__ s1cnt,
    int* __restrict__ s2cnt, int* __restrict__ bincnt) {
    const int b = blockIdx.x;
    const int t = threadIdx.x;
    for (int i = b * 256 + t; i < NBUK_MAX * BPAD; i += 8 * 256) bincnt[i] = 0;
    if (b == 0) {
        __shared__ int nzs[4];
        int nz = 0;
        for (int i = t; i < 4096; i += 256) nz |= (ei[2 * i + 1] != 0);
        unsigned long long bal = __ballot(nz);
        if ((t & 63) == 0) nzs[t >> 6] = (bal != 0ull) ? 1 : 0;
        __syncthreads();
        if (t == 0) {
            *flag = (nzs[0] | nzs[1] | nzs[2] | nzs[3]) ? 0 : 1;  // 1 = int64 input
            *s1cnt = 0;
            *s2cnt = 0;
        }
    }
}

// ---------------- K1: merged bin + Wc pack + x->bf16 (one launch) ----------------
// blocks [0, BINB): edge binning (LDS hist + range reserve + scatter);
// blocks [BINB, BINB+128): Wc pack; rest: xb conversion. The xb streaming
// blocks fill the machine and hide the bin blocks' latency/atomics.
__global__ __launch_bounds__(256) void bwx_kernel(
    const int* __restrict__ ei, const int* __restrict__ flag,
    int* __restrict__ bincnt, unsigned* __restrict__ bins,
    int* __restrict__ s1cnt, int* __restrict__ spill1, int E, int N, int NBUK,
    int BINB,
    const float* __restrict__ Wl, const float* __restrict__ Wr,
    unsigned short* __restrict__ Wc,
    const float4* __restrict__ x4, uint2* __restrict__ xb2, long total4) {
    const int b = blockIdx.x;
    const int t = threadIdx.x;

    if (b < BINB) {
        __shared__ int hist[NBUK_MAX];
        __shared__ int rbase[NBUK_MAX];
        const long e0 = (long)b * CHUNK;
        const int cnt = (int)min((long)CHUNK, (long)E - e0);
        const int is64 = *flag;

        for (int i = t; i < NBUK; i += 256) hist[i] = 0;
        __syncthreads();

        // phase A: histogram dst buckets
        for (int i = t; i < cnt; i += 256) {
            long e = e0 + i;
            int dst = is64 ? (int)((const long long*)ei)[(long)E + e] : ei[(long)E + e];
            dst = min(max(dst, 0), N - 1);
            atomicAdd(&hist[dst >> LOGB], 1);
        }
        __syncthreads();

        // phase B: reserve contiguous ranges (padded counters: 4/line not 32/line)
        for (int i = t; i < NBUK; i += 256) {
            int h = hist[i];
            rbase[i] = (h > 0) ? atomicAdd(&bincnt[i * BPAD], h) : 0;
            hist[i] = 0;  // reuse as bump counter
        }
        __syncthreads();

        // phase C: scatter packed entries (dst&127)<<25 | src
        for (int i = t; i < cnt; i += 256) {
            long e = e0 + i;
            int src, dst;
            if (is64) {
                src = (int)((const long long*)ei)[e];
                dst = (int)((const long long*)ei)[(long)E + e];
            } else {
                src = ei[e];
                dst = ei[(long)E + e];
            }
            src = min(max(src, 0), N - 1);
            dst = min(max(dst, 0), N - 1);
            int bk = dst >> LOGB;
            int slot = rbase[bk] + atomicAdd(&hist[bk], 1);
            if (slot < BCAP) {
                bins[(long)bk * BCAP + slot] =
                    ((unsigned)(dst & (LOCB - 1)) << 25) | (unsigned)src;
            } else {
                int sp = atomicAdd(s1cnt, 1);
                if (sp < S1CAP) {
                    spill1[2 * sp] = src;
                    spill1[2 * sp + 1] = dst;
                }
            }
        }
    } else if (b < BINB + 128) {
        int n = b - BINB;  // 0..127
        float w = (t < 128) ? Wl[n * 128 + t] : Wr[n * 128 + (t - 128)];
        Wc[n * 256 + t] = f2bf(w);
    } else {
        long gid = (long)(b - BINB - 128) * 256 + t;
        if (gid < total4) {
            float4 v = x4[gid];
            uint2 o;
            o.x = (unsigned)f2bf(v.x) | ((unsigned)f2bf(v.y) << 16);
            o.y = (unsigned)f2bf(v.z) | ((unsigned)f2bf(v.w) << 16);
            xb2[gid] = o;
        }
    }
}

// ---------------- K2: per-bucket CSR fill — LDS cursors + spill1 reinsert --------
__global__ __launch_bounds__(256) void fill2_kernel(
    const unsigned* __restrict__ bins, const int* __restrict__ bincnt,
    int* __restrict__ adj, int* __restrict__ cursor,
    const int* __restrict__ s1cnt, const int* __restrict__ spill1,
    int* __restrict__ s2cnt, int* __restrict__ spill2, int N) {
    __shared__ int cur[LOCB];
    const int bk = blockIdx.x;
    const int t = threadIdx.x;
    if (t < LOCB) cur[t] = 0;
    __syncthreads();
    const int cnt = min(bincnt[bk * BPAD], BCAP);
    const int nb = bk << LOGB;
    for (int i = t; i < cnt; i += 256) {
        unsigned v = bins[(long)bk * BCAP + i];
        int src = (int)(v & 0x1FFFFFFu);
        int ld = (int)(v >> 25);
        int slot = atomicAdd(&cur[ld], 1);
        int dst = nb + ld;
        if (slot < CAP) {
            adj[(long)dst * CAP + slot] = src;
        } else {
            int sp = atomicAdd(s2cnt, 1);
            if (sp < S2CAP) {
                spill2[2 * sp] = src;
                spill2[2 * sp + 1] = dst;
            }
        }
    }
    // re-insert this bucket's BCAP-overflow edges (normally zero entries)
    const int sc = min(*s1cnt, S1CAP);
    for (int i = t; i < sc; i += 256) {
        int dst = spill1[2 * i + 1];
        if ((dst >> LOGB) == bk) {
            int src = spill1[2 * i];
            int ld = dst & (LOCB - 1);
            int slot = atomicAdd(&cur[ld], 1);
            if (slot < CAP) {
                adj[(long)dst * CAP + slot] = src;
            } else {
                int sp = atomicAdd(s2cnt, 1);
                if (sp < S2CAP) {
                    spill2[2 * sp] = src;
                    spill2[2 * sp + 1] = dst;
                }
            }
        }
    }
    __syncthreads();
    if (t < LOCB && nb + t < N) cursor[nb + t] = cur[t];
}

__device__ __forceinline__ void acc_row(float* acc, uint4 v) {
    acc[0] += __builtin_bit_cast(float, v.x << 16);
    acc[1] += __builtin_bit_cast(float, v.x & 0xFFFF0000u);
    acc[2] += __builtin_bit_cast(float, v.y << 16);
    acc[3] += __builtin_bit_cast(float, v.y & 0xFFFF0000u);
    acc[4] += __builtin_bit_cast(float, v.z << 16);
    acc[5] += __builtin_bit_cast(float, v.z & 0xFFFF0000u);
    acc[6] += __builtin_bit_cast(float, v.w << 16);
    acc[7] += __builtin_bit_cast(float, v.w & 0xFFFF0000u);
}

// src for edge e of this quad's node; e >= cq redirects to row 0 (L1-hot).
__device__ __forceinline__ int pick_src(int adjv, int adjv2, int e, int cq, int qd) {
    int ec = e & 31;
    int s = __shfl((ec < 16) ? adjv : adjv2, qd * 16 + (ec & 15));
    return (e < cq) ? s : 0;
}

// ---------------- K3: fused gather + MFMA GEMM, 16 nodes per block ----------------
__global__ __launch_bounds__(256) void gg_kernel(
    const unsigned int* __restrict__ xb, const int* __restrict__ cursor,
    const int* __restrict__ adj, const unsigned short* __restrict__ Wc,
    const float* __restrict__ bl, float* __restrict__ out, int N) {
    __shared__ __align__(16) unsigned short A[16 * 264];

    const int t = threadIdx.x;
    const int wv = t >> 6;
    const int lane = t & 63;
    const int n0 = blockIdx.x * 16;
    const int fq = lane & 15;   // position within quad
    const int qd = lane >> 4;   // quad id = which of the wave's 4 nodes

    const int n = n0 + wv * 4 + qd;
    const int nc = min(n, N - 1);

    // independent front-loads: degree, adjacency (2x), own rows (4x)
    const int deg = (n < N) ? cursor[n] : 0;
    int adjv = adj[(long)nc * CAP + fq];
    int adjv2 = adj[(long)nc * CAP + 16 + fq];

    unsigned xv[4];
#pragma unroll
    for (int q = 0; q < 4; ++q) {
        int nn = n0 + wv * 4 + q;
        xv[q] = (nn < N) ? xb[(long)nn * 64 + lane] : 0u;
    }

    // clamp stored srcs (entries beyond deg are uninitialized garbage)
    adjv = min(max(adjv, 0), N - 1);
    adjv2 = min(max(adjv2, 0), N - 1);

    const int cq = min(deg, CAP);
    int mx = max(cq, __shfl_xor(cq, 16));
    mx = max(mx, __shfl_xor(mx, 32));
    mx = (mx + 3) & ~3;  // pad to chunk of 4

    float acc[8] = {0.f, 0.f, 0.f, 0.f, 0.f, 0.f, 0.f, 0.f};
    uint4 va[4], vb[4];
    // prefetch chunk 0
#pragma unroll
    for (int j = 0; j < 4; ++j) {
        int s = pick_src(adjv, adjv2, j, cq, qd);
        va[j] = *(const uint4*)&xb[(long)s * 64 + fq * 4];
    }
    for (int base = 0; base < mx; base += 4) {
        // issue next chunk's 4 loads before consuming current chunk
#pragma unroll
        for (int j = 0; j < 4; ++j) {
            int s = pick_src(adjv, adjv2, base + 4 + j, cq, qd);
            vb[j] = *(const uint4*)&xb[(long)s * 64 + fq * 4];
        }
#pragma unroll
        for (int j = 0; j < 4; ++j) {
            if (base + j < cq) acc_row(acc, va[j]);
        }
#pragma unroll
        for (int j = 0; j < 4; ++j) va[j] = vb[j];
    }

    const float iv = 1.0f / (float)max(deg, 1);
    uint4 o;
    o.x = (unsigned)f2bf(acc[0] * iv) | ((unsigned)f2bf(acc[1] * iv) << 16);
    o.y = (unsigned)f2bf(acc[2] * iv) | ((unsigned)f2bf(acc[3] * iv) << 16);
    o.z = (unsigned)f2bf(acc[4] * iv) | ((unsigned)f2bf(acc[5] * iv) << 16);
    o.w = (unsigned)f2bf(acc[6] * iv) | ((unsigned)f2bf(acc[7] * iv) << 16);
    *(uint4*)&A[(wv * 4 + qd) * 264 + fq * 8] = o;
#pragma unroll
    for (int q = 0; q < 4; ++q)
        *(unsigned*)&A[(wv * 4 + q) * 264 + 128 + 2 * lane] = xv[q];
    __syncthreads();

    // phase 2: MFMA — wave w computes cols [w*32, w*32+32)
    const int l15 = lane & 15;
    const int quad = lane >> 4;
    f32x4 acc2[2];
    acc2[0] = (f32x4){0.f, 0.f, 0.f, 0.f};
    acc2[1] = (f32x4){0.f, 0.f, 0.f, 0.f};

#pragma unroll
    for (int kc = 0; kc < 8; ++kc) {
        const int k0 = kc * 32;
        bf16x8 af = *(const bf16x8*)&A[l15 * 264 + k0 + quad * 8];
#pragma unroll
        for (int nt = 0; nt < 2; ++nt) {
            int col = wv * 32 + nt * 16 + l15;
            bf16x8 bf = *(const bf16x8*)&Wc[col * 256 + k0 + quad * 8];
            acc2[nt] = __builtin_amdgcn_mfma_f32_16x16x32_bf16(af, bf, acc2[nt], 0, 0, 0);
        }
    }

    // epilogue: C/D layout col=lane&15, row=quad*4+reg
#pragma unroll
    for (int nt = 0; nt < 2; ++nt) {
        int col = wv * 32 + nt * 16 + l15;
        float bias = bl[col];
#pragma unroll
        for (int r = 0; r < 4; ++r) {
            int node = n0 + quad * 4 + r;
            if (node < N) out[(long)node * 128 + col] = acc2[nt][r] + bias;
        }
    }
}

// ---------------- K4: exact CAP-overflow fixup (normally ~0 iterations) ----------
// For each spilled edge: out[dst][c] += (Wl[c] . x[src]) / deg[dst], in f32.
__global__ __launch_bounds__(256) void spill2_kernel(
    const float* __restrict__ x, const float* __restrict__ Wl,
    const int* __restrict__ cursor, const int* __restrict__ s2cnt,
    const int* __restrict__ spill2, float* __restrict__ out) {
    const int wv = threadIdx.x >> 6;
    const int lane = threadIdx.x & 63;
    const int sc = min(*s2cnt, S2CAP);
    for (int i = blockIdx.x * 4 + wv; i < sc; i += gridDim.x * 4) {
        int src = spill2[2 * i];
        int dst = spill2[2 * i + 1];
        float inv = 1.0f / (float)max(cursor[dst], 1);
#pragma unroll
        for (int cc = 0; cc < 2; ++cc) {
            int c = lane + cc * 64;
            float s = 0.0f;
            for (int k = 0; k < 128; k += 4) {
                float4 w4 = *(const float4*)&Wl[c * 128 + k];
                float4 x4 = *(const float4*)&x[(long)src * 128 + k];
                s += w4.x * x4.x + w4.y * x4.y + w4.z * x4.z + w4.w * x4.w;
            }
            atomicAdd(&out[(long)dst * 128 + c], s * inv);
        }
    }
}

extern "C" void kernel_launch(void* const* d_in, const int* in_sizes, int n_in,
                              void* d_out, int out_size, void* d_ws, size_t ws_size,
                              hipStream_t stream) {
    const float* x = (const float*)d_in[0];
    const int* ei = (const int*)d_in[1];
    const float* Wl = (const float*)d_in[2];
    const float* bl = (const float*)d_in[3];
    const float* Wr = (const float*)d_in[4];
    float* out = (float*)d_out;

    const int N = in_sizes[0] / D_FEAT;  // 100000
    const int E = in_sizes[1] / 2;       // 1600000
    const int NBUK = (N + LOCB - 1) >> LOGB;  // 782 (<= NBUK_MAX)
    const int BINB = (E + CHUNK - 1) / CHUNK; // 196

    int* wsI = (int*)d_ws;
    int* flag = wsI;                          // 64
    int* cursor = flag + 64;                  // N (degree after fill)
    int* s1cnt = cursor + N;                  // 64
    int* spill1 = s1cnt + 64;                 // 2*S1CAP
    int* s2cnt = spill1 + 2 * S1CAP;          // 64
    int* spill2 = s2cnt + 64;                 // 2*S2CAP
    int* bincnt = spill2 + 2 * S2CAP;         // NBUK_MAX*BPAD
    unsigned* bins = (unsigned*)(bincnt + NBUK_MAX * BPAD);       // NBUK*BCAP
    int* adj = (int*)(bins + (long)NBUK * BCAP);                  // N*CAP
    unsigned short* Wc = (unsigned short*)(adj + (long)N * CAP);  // 64KB
    unsigned int* xb = (unsigned int*)(Wc + 128 * 256);           // N*64 uints

    const long total4 = (long)N * 32;
    const int XBB = (int)((total4 + 255) / 256);

    tprep_kernel<<<8, 256, 0, stream>>>(ei, flag, s1cnt, s2cnt, bincnt);
    bwx_kernel<<<BINB + 128 + XBB, 256, 0, stream>>>(
        ei, flag, bincnt, bins, s1cnt, spill1, E, N, NBUK, BINB, Wl, Wr, Wc,
        (const float4*)x, (uint2*)xb, total4);
    fill2_kernel<<<NBUK, 256, 0, stream>>>(bins, bincnt, adj, cursor, s1cnt, spill1,
                                           s2cnt, spill2, N);
    gg_kernel<<<(N + 15) / 16, 256, 0, stream>>>(xb, cursor, adj, Wc, bl, out, N);
    spill2_kernel<<<64, 256, 0, stream>>>(x, Wl, cursor, s2cnt, spill2, out);
}